// Round 15
// baseline (1031.752 us; speedup 1.0000x reference)
//
#include <hip/hip_runtime.h>

#define BB 16
#define NN 8192
#define SS 512
#define N3 (3 * NN)  // 24576 elements per batch per tensor
#define KD 14        // per-lane depth for the SOLO (1-wave-per-row) fallback
#define KDB 7        // per-lane depth for the block-per-row kernel (32 pts/lane)

typedef unsigned short u16;
typedef unsigned int u32;
typedef unsigned long long u64;
typedef float v2f __attribute__((ext_vector_type(2)));

// Packed fp32 ops (VOP3P, 2 points/inst). Per-half rounding is IEEE rn —
// bit-identical to scalar __fadd_rn/__fmul_rn.
__device__ __forceinline__ v2f pk_add(v2f a, v2f b) {
  v2f r;
  asm("v_pk_add_f32 %0, %1, %2" : "=v"(r) : "v"(a), "v"(b));
  return r;
}
__device__ __forceinline__ v2f pk_mul(v2f a, v2f b) {
  v2f r;
  asm("v_pk_mul_f32 %0, %1, %2" : "=v"(r) : "v"(a), "v"(b));
  return r;
}

// u64 max step over a DPP lane-shift (FPS): old=0 is the max identity for our
// positive keys.
template <int CTRL>
__device__ __forceinline__ u64 dpp_maxk(u64 k) {
  u32 lo = (u32)k, hi = (u32)(k >> 32);
  u32 slo = (u32)__builtin_amdgcn_update_dpp(0, (int)lo, CTRL, 0xf, 0xf, false);
  u32 shi = (u32)__builtin_amdgcn_update_dpp(0, (int)hi, CTRL, 0xf, 0xf, false);
  u64 s = ((u64)shi << 32) | (u64)slo;
  return (s > k) ? s : k;
}
// u64 MIN step over a DPP lane-shift (KNN merges): old=self is the min
// identity.
template <int CTRL>
__device__ __forceinline__ u64 dpp_mink(u64 k) {
  u32 lo = (u32)k, hi = (u32)(k >> 32);
  u32 slo = (u32)__builtin_amdgcn_update_dpp((int)lo, (int)lo, CTRL, 0xf, 0xf, false);
  u32 shi = (u32)__builtin_amdgcn_update_dpp((int)hi, (int)hi, CTRL, 0xf, 0xf, false);
  u64 s = ((u64)shi << 32) | (u64)slo;
  return (s < k) ? s : k;
}
__device__ __forceinline__ u64 maxk(u64 a, u64 b) { return (a > b) ? a : b; }

// wave-min of `m` to ALL-lanes-usable form: 6-step DPP chain -> lane63, then
// 2 readlanes -> SGPR-uniform u64.
__device__ __forceinline__ u64 wave_min_u64(u64 m) {
  m = dpp_mink<0x111>(m);  // row_shr:1
  m = dpp_mink<0x112>(m);  // row_shr:2
  m = dpp_mink<0x114>(m);  // row_shr:4
  m = dpp_mink<0x118>(m);  // row_shr:8
  m = dpp_mink<0x142>(m);  // row_bcast:15
  m = dpp_mink<0x143>(m);  // row_bcast:31 -> lane63 = wave min
  u32 mlo = (u32)__builtin_amdgcn_readlane((int)(u32)m, 63);
  u32 mhi = (u32)__builtin_amdgcn_readlane((int)(u32)(m >> 32), 63);
  return ((u64)mhi << 32) | (u64)mlo;
}

// ---------------------------------------------------------------------------
// K1 (r27): FPS at 1024 thr = 4 waves/SIMD + prep (blocks 16..143, LDS-free,
// zero inter-block communication; stream order fences k_knn).
// History: r13 256thr(1w/SIMD) 544; r16 512thr(2w) 508; r14 1024thr(4w) 661
// — but r14 carried the OLD heavy per-wave overhead (~160 inst: 2 DPP chains
// + readlane + wave-find + 16-key reduce). r16's lean machinery (thread-local
// find + single u64 chain + VALU tree, ~90 inst) was never tested at 4
// waves/SIMD. r16 runs at 3.3x its issue model (big unhidden post-barrier
// spine: keys read -> tree -> coords read); 4 lean waves give 2x the TLP to
// hide it while per-wave dist work halves. Key algebra, tie-breaks, exact fp
// tree UNCHANGED -> bit-identical output.
// ---------------------------------------------------------------------------
__global__ __attribute__((amdgpu_flat_work_group_size(1024, 1024),
                          amdgpu_waves_per_eu(4, 4)))
void k_fps(const float* __restrict__ xyz, const float* __restrict__ pts,
           float* __restrict__ out_kp, float4* __restrict__ xyz4,
           float4* __restrict__ pts4, int do_prep) {
  __shared__ float sxyz[NN * 3];  // [idx][x,y,z] (FPS blocks only)
  __shared__ int sIdx[SS];
  __shared__ u64 rkey[2][16];
  int t = threadIdx.x;
  if (blockIdx.x >= BB) {
    // ---------------- prep plane ----------------
    if (do_prep) {
      int e = (blockIdx.x - BB) * 1024 + t;  // 128 blocks x 1024 = BB*NN
      int b = e >> 13, n = e & (NN - 1);
      const float* xb = xyz + b * N3;
      float x = xb[n], y = xb[NN + n], z = xb[2 * NN + n];
      float ww = __fadd_rn(__fadd_rn(__fmul_rn(x, x), __fmul_rn(y, y)),
                           __fmul_rn(z, z));
      xyz4[e] = make_float4(x, y, z, ww);
      const float* pb = pts + b * N3;
      pts4[e] = make_float4(pb[n], pb[NN + n], pb[2 * NN + n], 0.f);
    }
    return;
  }
  // ---------------- FPS (bit-exact vs numpy — see prior notes) ------------
  int b = blockIdx.x;
  const float* base = xyz + b * N3;
  v2f px[4], py[4], pz[4], dm[4];
#pragma unroll
  for (int j = 0; j < 4; ++j) {
    int n0 = j * 2048 + t, n1 = n0 + 1024;  // coalesced, disjoint cover [0,8192)
    px[j] = v2f{base[n0], base[n1]};
    py[j] = v2f{base[NN + n0], base[NN + n1]};
    pz[j] = v2f{base[2 * NN + n0], base[2 * NN + n1]};
    dm[j] = v2f{1e10f, 1e10f};
    sxyz[n0 * 3 + 0] = px[j].x;  // stage AoS copy for center re-loads
    sxyz[n0 * 3 + 1] = py[j].x;
    sxyz[n0 * 3 + 2] = pz[j].x;
    sxyz[n1 * 3 + 0] = px[j].y;
    sxyz[n1 * 3 + 1] = py[j].y;
    sxyz[n1 * 3 + 2] = pz[j].y;
  }
#pragma unroll
  for (int j = 0; j < 4; ++j) {
    // Opaque def: blocks rematerialization of the global loads.
    asm volatile("" : "+v"(px[j]), "+v"(py[j]), "+v"(pz[j]));
  }
  float cx = base[0], cy = base[NN], cz = base[2 * NN];
  int far = 0;
  int lane = t & 63, w = t >> 6;  // 16 waves
  u32 tb = (u32)(NN - t);  // candidate base: cand = NN - gidx (1..8192; 0=none)
  for (int it = 0; it < SS; ++it) {
    if (t == 0) sIdx[it] = far;  // scan emits carry BEFORE update: idx[0]=0
    v2f ncx = v2f{-cx, -cx}, ncy = v2f{-cy, -cy}, ncz = v2f{-cz, -cz};
    float vmax = 0.0f;
#pragma unroll
    for (int j = 0; j < 4; ++j) {
      v2f dx = pk_add(px[j], ncx);
      v2f dy = pk_add(py[j], ncy);
      v2f dz = pk_add(pz[j], ncz);
      v2f xx = pk_mul(dx, dx);
      v2f yy = pk_mul(dy, dy);
      v2f s = pk_add(xx, yy);
      v2f zz = pk_mul(dz, dz);
      v2f d = pk_add(s, zz);  // ((dx^2+dy^2)+dz^2), numpy tree per half
      float a0 = fminf(dm[j].x, d.x);
      float a1 = fminf(dm[j].y, d.y);
      dm[j].x = a0;
      dm[j].y = a1;
      vmax = fmaxf(vmax, fmaxf(a0, a1));  // max3-foldable
    }
    // thread-local find vs OWN max: exact bit-equality (vmax IS one of this
    // thread's dm values). Descending gidx -> LAST write = lowest gidx.
    u32 cand = 0;
#pragma unroll
    for (int j = 3; j >= 0; --j) {
      u32 v1 = tb - (u32)(j * 2048 + 1024);  // .y half (higher gidx)
      u32 v0 = tb - (u32)(j * 2048);         // .x half
      cand = (dm[j].y == vmax) ? v1 : cand;
      cand = (dm[j].x == vmax) ? v0 : cand;
    }
    // 6-step DPP u64 max chain -> lane63 = wave best (max dist, tie -> max
    // cand = min gidx). VALU pipe only.
    u64 key = ((u64)__float_as_uint(vmax) << 32) | cand;
    key = dpp_maxk<0x111>(key);  // row_shr:1
    key = dpp_maxk<0x112>(key);  // row_shr:2
    key = dpp_maxk<0x114>(key);  // row_shr:4
    key = dpp_maxk<0x118>(key);  // row_shr:8
    key = dpp_maxk<0x142>(key);  // row_bcast:15
    key = dpp_maxk<0x143>(key);  // row_bcast:31 -> lane63 = wave max
    int pb = it & 1;  // parity double-buffer: safe with one barrier/iter
    if (lane == 63) rkey[pb][w] = key;
    __syncthreads();  // the only barrier per iteration
    // block reduce over 16 wave keys: every thread broadcast-reads all 16
    // slots (pipelined b128 reads) + redundant VALU tree. No cross-lane ops.
    u64 kk0 = rkey[pb][0], kk1 = rkey[pb][1];
    u64 kk2 = rkey[pb][2], kk3 = rkey[pb][3];
    u64 kk4 = rkey[pb][4], kk5 = rkey[pb][5];
    u64 kk6 = rkey[pb][6], kk7 = rkey[pb][7];
    u64 kk8 = rkey[pb][8], kk9 = rkey[pb][9];
    u64 kk10 = rkey[pb][10], kk11 = rkey[pb][11];
    u64 kk12 = rkey[pb][12], kk13 = rkey[pb][13];
    u64 kk14 = rkey[pb][14], kk15 = rkey[pb][15];
    u64 m01 = maxk(kk0, kk1), m23 = maxk(kk2, kk3);
    u64 m45 = maxk(kk4, kk5), m67 = maxk(kk6, kk7);
    u64 m89 = maxk(kk8, kk9), mab = maxk(kk10, kk11);
    u64 mcd = maxk(kk12, kk13), mef = maxk(kk14, kk15);
    u64 q0 = maxk(m01, m23), q1 = maxk(m45, m67);
    u64 q2 = maxk(m89, mab), q3 = maxk(mcd, mef);
    u64 kg = maxk(maxk(q0, q1), maxk(q2, q3));
    far = NN - (int)(u32)(kg & 0xffffffffu);
    // broadcast ds_read of the winner's coords (all lanes same address)
    cx = sxyz[far * 3 + 0];
    cy = sxyz[far * 3 + 1];
    cz = sxyz[far * 3 + 2];
  }
  __syncthreads();
  for (int i = t; i < SS; i += 1024) {
    int id = sIdx[i];
    out_kp[b * 1536 + i] = base[id];  // exact fp32 copies
    out_kp[b * 1536 + SS + i] = base[NN + id];
    out_kp[b * 1536 + 2 * SS + i] = base[2 * NN + id];
  }
}

// ---------------------------------------------------------------------------
// K2 (r21, unchanged): one ROW per 256-thread BLOCK. 32 pts/lane, KDB=7
// (failure odds ~8e-8/run). 3-level exact min-extract merge -> bit-identical
// to the 1-wave version. 985 -> 904 us win.
// ---------------------------------------------------------------------------
__global__ __launch_bounds__(256) void k_knn_blk(const float4* __restrict__ xyz4,
                                                 const float* __restrict__ kp,
                                                 u16* __restrict__ knn) {
  __shared__ u64 skeys[96];
  int t = threadIdx.x, lane = t & 63, w = t >> 6;
  int b = blockIdx.x >> 9, s = blockIdx.x & (SS - 1);
  const float4* base4 = xyz4 + (b << 13);
  float ax = kp[b * 1536 + s];
  float ay = kp[b * 1536 + SS + s];
  float az = kp[b * 1536 + 2 * SS + s];
  float aw = __fadd_rn(__fadd_rn(__fmul_rn(ax, ax), __fmul_rn(ay, ay)), __fmul_rn(az, az));
  u64 arr[KDB];
#pragma unroll
  for (int i = 0; i < KDB; ++i) arr[i] = ~0ull;
  for (int c = 0; c < 32; ++c) {
    int n = c * 256 + t;  // coalesced across the block, disjoint cover
    float4 q = base4[n];  // one dwordx4
    float dot = __fadd_rn(__fadd_rn(__fmul_rn(ax, q.x), __fmul_rn(ay, q.y)),
                          __fmul_rn(az, q.z));
    float d = __fsub_rn(__fadd_rn(aw, q.w), __fmul_rn(2.0f, dot));
    u32 ub = __float_as_uint(d);
    ub ^= (ub & 0x80000000u) ? 0xFFFFFFFFu : 0x80000000u;  // order-preserving map
    u64 key = ((u64)ub << 32) | (u32)n;
    if (key < arr[KDB - 1]) {  // sorted insert, CSE'd conditions
      bool cg[KDB];
#pragma unroll
      for (int i = 0; i < KDB; ++i) cg[i] = arr[i] > key;
#pragma unroll
      for (int i = KDB - 1; i >= 1; --i)
        arr[i] = cg[i - 1] ? arr[i - 1] : (cg[i] ? key : arr[i]);
      arr[0] = cg[0] ? key : arr[0];
    }
  }
  // phase A: per-wave merge of 64 sorted lists -> wave's sorted top-24
  u64 mine = 0;
  for (int it = 0; it < 24; ++it) {
    u64 mw = wave_min_u64(arr[0]);
    if (lane == it) mine = mw;
    if (arr[0] == mw) {  // unique keys -> exactly one popper
#pragma unroll
      for (int i = 0; i < KDB - 1; ++i) arr[i] = arr[i + 1];
      arr[KDB - 1] = ~0ull;
    }
  }
  if (lane < 24) skeys[w * 24 + lane] = mine;
  __syncthreads();
  // phase B: wave 0 merges the 4 sorted 24-lists (96 unique keys)
  if (w == 0) {
    u64 a = skeys[lane];
    u64 b2 = (lane < 32) ? skeys[64 + lane] : ~0ull;
    u64 lo = (a < b2) ? a : b2;
    u64 hi = (a < b2) ? b2 : a;
    u64 outk = 0;
    for (int it = 0; it < 24; ++it) {
      u64 mw = wave_min_u64(lo);
      if (lane == it) outk = mw;
      if (lo == mw) {
        lo = hi;
        hi = ~0ull;
      }
    }
    if (lane < 24) knn[blockIdx.x * 24 + lane] = (u16)(outk & 0xFFFFu);
  }
}

// ---------------------------------------------------------------------------
// Fallback solo KNN (workspace too small for float4): scalar path, 1 wave
// per row, KD=14.
// ---------------------------------------------------------------------------
__global__ __launch_bounds__(256) void k_knn_solo(const float* __restrict__ xyz,
                                                  const float* __restrict__ kp,
                                                  u16* __restrict__ knn) {
  int t = threadIdx.x;
  int row = blockIdx.x * 4 + (t >> 6);
  int lane = t & 63;
  int b = row >> 9, s = row & (SS - 1);
  const float* base = xyz + b * N3;
  float ax = kp[b * 1536 + s];
  float ay = kp[b * 1536 + SS + s];
  float az = kp[b * 1536 + 2 * SS + s];
  float aw = __fadd_rn(__fadd_rn(__fmul_rn(ax, ax), __fmul_rn(ay, ay)), __fmul_rn(az, az));
  u64 arr[KD];
#pragma unroll
  for (int i = 0; i < KD; ++i) arr[i] = ~0ull;
  for (int c = 0; c < 128; ++c) {
    int n = c * 64 + lane;
    float qx = base[n], qy = base[NN + n], qz = base[2 * NN + n];
    float qw = __fadd_rn(__fadd_rn(__fmul_rn(qx, qx), __fmul_rn(qy, qy)), __fmul_rn(qz, qz));
    float dot = __fadd_rn(__fadd_rn(__fmul_rn(ax, qx), __fmul_rn(ay, qy)), __fmul_rn(az, qz));
    float d = __fsub_rn(__fadd_rn(aw, qw), __fmul_rn(2.0f, dot));
    u32 ub = __float_as_uint(d);
    ub ^= (ub & 0x80000000u) ? 0xFFFFFFFFu : 0x80000000u;
    u64 key = ((u64)ub << 32) | (u32)n;
    if (key < arr[KD - 1]) {
      bool cg[KD];
#pragma unroll
      for (int i = 0; i < KD; ++i) cg[i] = arr[i] > key;
#pragma unroll
      for (int i = KD - 1; i >= 1; --i)
        arr[i] = cg[i - 1] ? arr[i - 1] : (cg[i] ? key : arr[i]);
      arr[0] = cg[0] ? key : arr[0];
    }
  }
  u64 mine = 0;
  for (int it = 0; it < 24; ++it) {
    u64 mw = wave_min_u64(arr[0]);
    if (lane == it) mine = mw;
    if (arr[0] == mw) {
#pragma unroll
      for (int i = 0; i < KD - 1; ++i) arr[i] = arr[i + 1];
      arr[KD - 1] = ~0ull;
    }
  }
  if (lane < 24) knn[row * 24 + lane] = (u16)(mine & 0xFFFFu);
}

// ---------------------------------------------------------------------------
// K3 (r26 = r22 verbatim — the proven best): fused base-SA + multi-scale
// MLPs, 256 thr, TWO channels/thread (wgtA/wgtB = 2-way ILP in h2). W2 staged
// TRANSPOSED into LDS once (coalesced global reads), wgt regs filled from LDS
// then ASM-PINNED (blocks remat). W2T buffer aliases sfeat/sh1 (dead after
// the fill). r23-r25 occupancy experiments all regressed — do not revisit.
// ---------------------------------------------------------------------------
template <int USE4>
__global__ __launch_bounds__(256) void k_mlp(
    const float* __restrict__ xyz, const float* __restrict__ pts,
    const float4* __restrict__ xyz4, const float4* __restrict__ pts4,
    const float* __restrict__ kp, const u16* __restrict__ knn,
    const float* __restrict__ W1, const float* __restrict__ b1,
    const float* __restrict__ W2, const float* __restrict__ b2,
    const float* __restrict__ msW1, const float* __restrict__ msb1,
    const float* __restrict__ msW2, const float* __restrict__ msb2,
    float* __restrict__ out) {
  __shared__ float smem[448 + 8320];  // persistent 448 | big 8320 (35KB)
  float* sW1T = smem;                 // [c][o] (384 base / 192 ms)
  float* sb1 = smem + 384;            // 64
  float* big = smem + 448;            // W2T during init; sfeat|sh1 in groups
  int t = threadIdx.x, lane = t & 63, w = t >> 6;
  int b = blockIdx.x >> 6, s0 = (blockIdx.x & 63) * 8;
  int scale = (int)blockIdx.y - 1;  // -1 for base plane
  float b2A, b2B;
  const float* W2src;
  if (blockIdx.y == 0) {
    for (int i = t; i < 384; i += 256) {
      int o = i / 6, c = i - o * 6;
      sW1T[c * 64 + o] = W1[i];
    }
    if (t < 64) sb1[t] = b1[t];
    W2src = W2;
    b2A = b2[lane];
    b2B = b2[lane + 64];
  } else {
    const float* W1s = msW1 + scale * 192;
    for (int i = t; i < 192; i += 256) {
      int o = i / 3, c = i - o * 3;
      sW1T[c * 64 + o] = W1s[i];
    }
    if (t < 64) sb1[t] = msb1[scale * 64 + t];
    W2src = msW2 + scale * 8192;
    b2A = msb2[scale * 128 + lane];
    b2B = msb2[scale * 128 + lane + 64];
  }
  // Stage W2 transposed: big[j*130 + row]. Global reads coalesced (32/thread);
  // LDS writes 2-way bank aliased (free).
  for (int i = t; i < 8192; i += 256) {
    int row = i >> 6, j = i & 63;
    big[j * 130 + row] = W2src[i];
  }
  __syncthreads();
  float wgtA[64], wgtB[64];
#pragma unroll
  for (int j = 0; j < 64; ++j) {
    wgtA[j] = big[j * 130 + lane];       // 2-way bank, free
    wgtB[j] = big[j * 130 + 64 + lane];  // ds_read2-pairable
  }
#pragma unroll
  for (int j = 0; j < 64; ++j) {
    // Opaque def: forces true VGPR residency (blocks remat/spill-reload).
    asm volatile("" : "+v"(wgtA[j]), "+v"(wgtB[j]));
  }
  __syncthreads();  // all reg fills done before groups overwrite `big`
  if (blockIdx.y == 0) {
    // ---------------- base plane ----------------
    float* sfeat = big;        // [row][k*6+c] 4*96
    float* sh1 = big + 384;    // [row][k*64+o] 4*1024
    for (int g = 0; g < 2; ++g) {
      if (t < 128) {  // 64 (rr,k) pairs x 2 halves: h=0 xyz, h=1 pts
        int p = t >> 1, h = t & 1;
        int rr = p >> 4, k = p & 15;
        int s = s0 + g * 4 + rr, row = b * SS + s;
        int id = knn[row * 24 + k];  // first 16 of sorted top-24 = base KNN
        float* f = &sfeat[rr * 96 + k * 6];
        if (h == 0) {
          float qx, qy, qz;
          if constexpr (USE4) {
            float4 q = xyz4[(b << 13) + id];
            qx = q.x; qy = q.y; qz = q.z;
          } else {
            qx = xyz[b * N3 + id];
            qy = xyz[b * N3 + NN + id];
            qz = xyz[b * N3 + 2 * NN + id];
          }
          f[0] = __fsub_rn(qx, kp[b * 1536 + s]);
          f[1] = __fsub_rn(qy, kp[b * 1536 + SS + s]);
          f[2] = __fsub_rn(qz, kp[b * 1536 + 2 * SS + s]);
        } else {
          float px_, py_, pz_;
          if constexpr (USE4) {
            float4 q = pts4[(b << 13) + id];
            px_ = q.x; py_ = q.y; pz_ = q.z;
          } else {
            px_ = pts[b * N3 + id];
            py_ = pts[b * N3 + NN + id];
            pz_ = pts[b * N3 + 2 * NN + id];
          }
          f[3] = px_;
          f[4] = py_;
          f[5] = pz_;
        }
      }
      __syncthreads();
#pragma unroll
      for (int m = 0; m < 16; ++m) {  // 4 rows x 1024 h1 entries / 256 thr
        int u = m * 256 + t;
        int rr = u >> 10, rem = u & 1023, k = rem >> 6, o = rem & 63;
        float acc = sb1[o];
#pragma unroll
        for (int c = 0; c < 6; ++c) acc = fmaf(sfeat[rr * 96 + k * 6 + c], sW1T[c * 64 + o], acc);
        sh1[rr * 1024 + k * 64 + o] = fmaxf(acc, 0.f);
      }
      __syncthreads();
      float bestA = -1e30f, bestB = -1e30f;
#pragma unroll
      for (int k = 0; k < 16; ++k) {
        const float4* h4 = (const float4*)&sh1[w * 1024 + k * 64];  // wave-uniform bcast
        float a0 = 0.f, a1 = 0.f;
#pragma unroll
        for (int j = 0; j < 16; ++j) {
          float4 hv = h4[j];
          a0 = fmaf(hv.x, wgtA[4 * j], a0);
          a0 = fmaf(hv.y, wgtA[4 * j + 1], a0);
          a0 = fmaf(hv.z, wgtA[4 * j + 2], a0);
          a0 = fmaf(hv.w, wgtA[4 * j + 3], a0);
          a1 = fmaf(hv.x, wgtB[4 * j], a1);
          a1 = fmaf(hv.y, wgtB[4 * j + 1], a1);
          a1 = fmaf(hv.z, wgtB[4 * j + 2], a1);
          a1 = fmaf(hv.w, wgtB[4 * j + 3], a1);
        }
        bestA = fmaxf(bestA, a0);
        bestB = fmaxf(bestB, a1);
      }
      int s = s0 + g * 4 + w;
      out[24576 + b * 262144 + lane * 512 + s] = bestA + b2A;
      out[24576 + b * 262144 + (lane + 64) * 512 + s] = bestB + b2B;
      __syncthreads();  // protect sfeat/sh1 before next group overwrites
    }
  } else {
    // ---------------- ms planes (kk = 8*(scale+1)) ----------------
    int kk = 8 * (scale + 1);
    float* sfeat = big;        // [row][k*3+c] 4*72
    float* sh1 = big + 288;    // [row][k*64+o] 4*1536
    int co = 128 * (scale + 1);
    for (int g = 0; g < 2; ++g) {
      if (t < 96) {  // 4 rows x 24 slots (stage all 24; h1 reads only k<kk)
        int rr = t / 24, k = t - rr * 24;  // constant divisor -> mul-shift
        int s = s0 + g * 4 + rr, row = b * SS + s;
        int id = knn[row * 24 + k];
        float qx, qy, qz;
        if constexpr (USE4) {
          float4 q = xyz4[(b << 13) + id];
          qx = q.x; qy = q.y; qz = q.z;
        } else {
          qx = xyz[b * N3 + id];
          qy = xyz[b * N3 + NN + id];
          qz = xyz[b * N3 + 2 * NN + id];
        }
        float* f = &sfeat[rr * 72 + k * 3];
        f[0] = __fsub_rn(qx, kp[b * 1536 + s]);
        f[1] = __fsub_rn(qy, kp[b * 1536 + SS + s]);
        f[2] = __fsub_rn(qz, kp[b * 1536 + 2 * SS + s]);
      }
      __syncthreads();
      for (int rr = 0; rr < 4; ++rr) {  // h1 for kk*64 entries per row
        for (int u = t; u < kk * 64; u += 256) {
          int k = u >> 6, o = u & 63;
          float acc = sb1[o];
          acc = fmaf(sfeat[rr * 72 + k * 3 + 0], sW1T[o], acc);
          acc = fmaf(sfeat[rr * 72 + k * 3 + 1], sW1T[64 + o], acc);
          acc = fmaf(sfeat[rr * 72 + k * 3 + 2], sW1T[128 + o], acc);
          sh1[rr * 1536 + k * 64 + o] = fmaxf(acc, 0.f);
        }
      }
      __syncthreads();
      float bestA = -1e30f, bestB = -1e30f;
      for (int k = 0; k < kk; ++k) {  // kk uniform across block -> no divergence
        const float4* h4 = (const float4*)&sh1[w * 1536 + k * 64];
        float a0 = 0.f, a1 = 0.f;
#pragma unroll
        for (int j = 0; j < 16; ++j) {
          float4 hv = h4[j];
          a0 = fmaf(hv.x, wgtA[4 * j], a0);
          a0 = fmaf(hv.y, wgtA[4 * j + 1], a0);
          a0 = fmaf(hv.z, wgtA[4 * j + 2], a0);
          a0 = fmaf(hv.w, wgtA[4 * j + 3], a0);
          a1 = fmaf(hv.x, wgtB[4 * j], a1);
          a1 = fmaf(hv.y, wgtB[4 * j + 1], a1);
          a1 = fmaf(hv.z, wgtB[4 * j + 2], a1);
          a1 = fmaf(hv.w, wgtB[4 * j + 3], a1);
        }
        bestA = fmaxf(bestA, a0);
        bestB = fmaxf(bestB, a1);
      }
      int s = s0 + g * 4 + w;
      out[24576 + b * 262144 + (co + lane) * 512 + s] = bestA + b2A;
      out[24576 + b * 262144 + (co + lane + 64) * 512 + s] = bestB + b2B;
      __syncthreads();
    }
  }
}

// ---------------------------------------------------------------------------
extern "C" void kernel_launch(void* const* d_in, const int* in_sizes, int n_in,
                              void* d_out, int out_size, void* d_ws, size_t ws_size,
                              hipStream_t stream) {
  const float* xyz = (const float*)d_in[0];    // l0_xyz  [B,3,N] f32
  const float* pts = (const float*)d_in[1];    // l0_points
  const float* sa_W1 = (const float*)d_in[2];  // [64,6]
  const float* sa_b1 = (const float*)d_in[3];  // [64]
  const float* sa_W2 = (const float*)d_in[4];  // [128,64]
  const float* sa_b2 = (const float*)d_in[5];  // [128]
  const float* ms_W1 = (const float*)d_in[6];  // [3,64,3]
  const float* ms_b1 = (const float*)d_in[7];  // [3,64]
  const float* ms_W2 = (const float*)d_in[8];  // [3,128,64]
  const float* ms_b2 = (const float*)d_in[9];  // [3,128]
  float* out = (float*)d_out;
  const float* kp = (const float*)d_out;  // keypoints written by k_fps

  // workspace: knn u16[B*S*24] = 393216 B, then xyz4/pts4 float4[B*N] = 2 MB each
  u16* knn = (u16*)d_ws;
  float4* xyz4 = (float4*)((char*)d_ws + 393216);
  float4* pts4 = xyz4 + BB * NN;
  const size_t need4 = 393216 + (size_t)2 * BB * NN * sizeof(float4);
  const bool use4 = ws_size >= need4;

  k_fps<<<BB + 128, 1024, 0, stream>>>(xyz, pts, out, xyz4, pts4, use4 ? 1 : 0);
  if (use4) {
    k_knn_blk<<<BB * SS, 256, 0, stream>>>(xyz4, kp, knn);
    k_mlp<1><<<dim3(BB * 64, 4), 256, 0, stream>>>(xyz, pts, xyz4, pts4, kp, knn,
                                                   sa_W1, sa_b1, sa_W2, sa_b2,
                                                   ms_W1, ms_b1, ms_W2, ms_b2, out);
  } else {
    k_knn_solo<<<(BB * SS) / 4, 256, 0, stream>>>(xyz, kp, knn);
    k_mlp<0><<<dim3(BB * 64, 4), 256, 0, stream>>>(xyz, pts, xyz4, pts4, kp, knn,
                                                   sa_W1, sa_b1, sa_W2, sa_b2,
                                                   ms_W1, ms_b1, ms_W2, ms_b2, out);
  }
}

// Round 16
// 885.976 us; speedup vs baseline: 1.1645x; 1.1645x over previous
//
#include <hip/hip_runtime.h>

#define BB 16
#define NN 8192
#define SS 512
#define N3 (3 * NN)  // 24576 elements per batch per tensor
#define KD 14        // per-lane depth for the SOLO (1-wave-per-row) fallback
#define KDB 7        // per-lane depth for the block-per-row kernel (32 pts/lane)

typedef unsigned short u16;
typedef unsigned int u32;
typedef unsigned long long u64;
typedef float v2f __attribute__((ext_vector_type(2)));

// Packed fp32 ops (VOP3P, 2 points/inst). Per-half rounding is IEEE rn —
// bit-identical to scalar __fadd_rn/__fmul_rn.
__device__ __forceinline__ v2f pk_add(v2f a, v2f b) {
  v2f r;
  asm("v_pk_add_f32 %0, %1, %2" : "=v"(r) : "v"(a), "v"(b));
  return r;
}
__device__ __forceinline__ v2f pk_mul(v2f a, v2f b) {
  v2f r;
  asm("v_pk_mul_f32 %0, %1, %2" : "=v"(r) : "v"(a), "v"(b));
  return r;
}

// u64 max step over a DPP lane-shift (FPS): old=0 is the max identity for our
// positive keys.
template <int CTRL>
__device__ __forceinline__ u64 dpp_maxk(u64 k) {
  u32 lo = (u32)k, hi = (u32)(k >> 32);
  u32 slo = (u32)__builtin_amdgcn_update_dpp(0, (int)lo, CTRL, 0xf, 0xf, false);
  u32 shi = (u32)__builtin_amdgcn_update_dpp(0, (int)hi, CTRL, 0xf, 0xf, false);
  u64 s = ((u64)shi << 32) | (u64)slo;
  return (s > k) ? s : k;
}
// u64 MIN step over a DPP lane-shift (KNN merges): old=self is the min
// identity.
template <int CTRL>
__device__ __forceinline__ u64 dpp_mink(u64 k) {
  u32 lo = (u32)k, hi = (u32)(k >> 32);
  u32 slo = (u32)__builtin_amdgcn_update_dpp((int)lo, (int)lo, CTRL, 0xf, 0xf, false);
  u32 shi = (u32)__builtin_amdgcn_update_dpp((int)hi, (int)hi, CTRL, 0xf, 0xf, false);
  u64 s = ((u64)shi << 32) | (u64)slo;
  return (s < k) ? s : k;
}
__device__ __forceinline__ u64 maxk(u64 a, u64 b) { return (a > b) ? a : b; }

// wave-min of `m` to ALL-lanes-usable form: 6-step DPP chain -> lane63, then
// 2 readlanes -> SGPR-uniform u64.
__device__ __forceinline__ u64 wave_min_u64(u64 m) {
  m = dpp_mink<0x111>(m);  // row_shr:1
  m = dpp_mink<0x112>(m);  // row_shr:2
  m = dpp_mink<0x114>(m);  // row_shr:4
  m = dpp_mink<0x118>(m);  // row_shr:8
  m = dpp_mink<0x142>(m);  // row_bcast:15
  m = dpp_mink<0x143>(m);  // row_bcast:31 -> lane63 = wave min
  u32 mlo = (u32)__builtin_amdgcn_readlane((int)(u32)m, 63);
  u32 mhi = (u32)__builtin_amdgcn_readlane((int)(u32)(m >> 32), 63);
  return ((u64)mhi << 32) | (u64)mlo;
}

// ---------------------------------------------------------------------------
// K1 (r26 config — REVERTED to the proven best after r27's 4-wave regression):
// FPS at 512 thr = 2 waves/SIMD (measured optimum: 1w 544, 2w 508, 4w-lean
// 669 — time tracks per-SIMD issue; per-wave fixed overhead x wave count
// dominates, latency already part-hidden at 2 waves) + prep (blocks 16..143,
// LDS-free, zero inter-block communication; stream order fences k_knn; prep
// fully hidden under FPS — verified 512us incl. prep).
// FPS core bit-exact vs numpy: thread-local find vs OWN vmax (bit-equality;
// descending gidx -> lowest idx on ties), key = dist<<32 | (NN-idx) so max
// key = max dist tie-> lowest idx = np.argmax; DPP-only cross-lane (r15:
// shfl = ds_bpermute LDS latency, avoid); ONE barrier/iter; parity
// double-buffer on rkey; broadcast LDS reads for keys + winner coords.
// ---------------------------------------------------------------------------
__global__ __attribute__((amdgpu_flat_work_group_size(512, 512),
                          amdgpu_waves_per_eu(2, 2)))
void k_fps(const float* __restrict__ xyz, const float* __restrict__ pts,
           float* __restrict__ out_kp, float4* __restrict__ xyz4,
           float4* __restrict__ pts4, int do_prep) {
  __shared__ float sxyz[NN * 3];  // [idx][x,y,z] (FPS blocks only)
  __shared__ int sIdx[SS];
  __shared__ u64 rkey[2][8];
  int t = threadIdx.x;
  if (blockIdx.x >= BB) {
    // ---------------- prep plane ----------------
    if (do_prep) {
      int e0 = (blockIdx.x - BB) * 1024 + t;  // 128 blocks x 1024 elems
#pragma unroll
      for (int r = 0; r < 2; ++r) {
        int e = e0 + r * 512;  // coalesced; covers [0, BB*NN)
        int b = e >> 13, n = e & (NN - 1);
        const float* xb = xyz + b * N3;
        float x = xb[n], y = xb[NN + n], z = xb[2 * NN + n];
        float ww = __fadd_rn(__fadd_rn(__fmul_rn(x, x), __fmul_rn(y, y)),
                             __fmul_rn(z, z));
        xyz4[e] = make_float4(x, y, z, ww);
        const float* pb = pts + b * N3;
        pts4[e] = make_float4(pb[n], pb[NN + n], pb[2 * NN + n], 0.f);
      }
    }
    return;
  }
  // ---------------- FPS ----------------
  int b = blockIdx.x;
  const float* base = xyz + b * N3;
  v2f px[8], py[8], pz[8], dm[8];
#pragma unroll
  for (int j = 0; j < 8; ++j) {
    int n0 = j * 1024 + t, n1 = n0 + 512;  // coalesced, disjoint cover [0,8192)
    px[j] = v2f{base[n0], base[n1]};
    py[j] = v2f{base[NN + n0], base[NN + n1]};
    pz[j] = v2f{base[2 * NN + n0], base[2 * NN + n1]};
    dm[j] = v2f{1e10f, 1e10f};
    sxyz[n0 * 3 + 0] = px[j].x;  // stage AoS copy for center re-loads
    sxyz[n0 * 3 + 1] = py[j].x;
    sxyz[n0 * 3 + 2] = pz[j].x;
    sxyz[n1 * 3 + 0] = px[j].y;
    sxyz[n1 * 3 + 1] = py[j].y;
    sxyz[n1 * 3 + 2] = pz[j].y;
  }
#pragma unroll
  for (int j = 0; j < 8; ++j) {
    // Opaque def: blocks rematerialization of the global loads.
    asm volatile("" : "+v"(px[j]), "+v"(py[j]), "+v"(pz[j]));
  }
  float cx = base[0], cy = base[NN], cz = base[2 * NN];
  int far = 0;
  int lane = t & 63, w = t >> 6;
  u32 tb = (u32)(NN - t);  // candidate base: cand = NN - gidx (1..8192; 0=none)
  for (int it = 0; it < SS; ++it) {
    if (t == 0) sIdx[it] = far;  // scan emits carry BEFORE update: idx[0]=0
    v2f ncx = v2f{-cx, -cx}, ncy = v2f{-cy, -cy}, ncz = v2f{-cz, -cz};
    float vmax = 0.0f;
#pragma unroll
    for (int j = 0; j < 8; ++j) {
      v2f dx = pk_add(px[j], ncx);
      v2f dy = pk_add(py[j], ncy);
      v2f dz = pk_add(pz[j], ncz);
      v2f xx = pk_mul(dx, dx);
      v2f yy = pk_mul(dy, dy);
      v2f s = pk_add(xx, yy);
      v2f zz = pk_mul(dz, dz);
      v2f d = pk_add(s, zz);  // ((dx^2+dy^2)+dz^2), numpy tree per half
      float a0 = fminf(dm[j].x, d.x);
      float a1 = fminf(dm[j].y, d.y);
      dm[j].x = a0;
      dm[j].y = a1;
      vmax = fmaxf(vmax, fmaxf(a0, a1));  // max3-foldable
    }
    u32 cand = 0;
#pragma unroll
    for (int j = 7; j >= 0; --j) {
      u32 v1 = tb - (u32)(j * 1024 + 512);  // cand for .y half (higher gidx)
      u32 v0 = tb - (u32)(j * 1024);        // cand for .x half
      cand = (dm[j].y == vmax) ? v1 : cand;
      cand = (dm[j].x == vmax) ? v0 : cand;
    }
    u64 key = ((u64)__float_as_uint(vmax) << 32) | cand;
    key = dpp_maxk<0x111>(key);  // row_shr:1
    key = dpp_maxk<0x112>(key);  // row_shr:2
    key = dpp_maxk<0x114>(key);  // row_shr:4
    key = dpp_maxk<0x118>(key);  // row_shr:8
    key = dpp_maxk<0x142>(key);  // row_bcast:15
    key = dpp_maxk<0x143>(key);  // row_bcast:31 -> lane63 = wave max
    int pb = it & 1;  // parity double-buffer: safe with one barrier/iter
    if (lane == 63) rkey[pb][w] = key;
    __syncthreads();  // the only barrier per iteration
    u64 k0 = rkey[pb][0], k1 = rkey[pb][1];
    u64 k2 = rkey[pb][2], k3 = rkey[pb][3];
    u64 k4 = rkey[pb][4], k5 = rkey[pb][5];
    u64 k6 = rkey[pb][6], k7 = rkey[pb][7];
    u64 kg = maxk(maxk(maxk(k0, k1), maxk(k2, k3)),
                  maxk(maxk(k4, k5), maxk(k6, k7)));
    far = NN - (int)(u32)(kg & 0xffffffffu);
    cx = sxyz[far * 3 + 0];
    cy = sxyz[far * 3 + 1];
    cz = sxyz[far * 3 + 2];
  }
  __syncthreads();
  for (int i = t; i < SS; i += 512) {
    int id = sIdx[i];
    out_kp[b * 1536 + i] = base[id];  // exact fp32 copies
    out_kp[b * 1536 + SS + i] = base[NN + id];
    out_kp[b * 1536 + 2 * SS + i] = base[2 * NN + id];
  }
}

// ---------------------------------------------------------------------------
// K2 (r21, unchanged): one ROW per 256-thread BLOCK. 32 pts/lane, KDB=7
// (failure odds ~8e-8/run). 3-level exact min-extract merge -> bit-identical
// to the 1-wave version. 985 -> 904 us win.
// ---------------------------------------------------------------------------
__global__ __launch_bounds__(256) void k_knn_blk(const float4* __restrict__ xyz4,
                                                 const float* __restrict__ kp,
                                                 u16* __restrict__ knn) {
  __shared__ u64 skeys[96];
  int t = threadIdx.x, lane = t & 63, w = t >> 6;
  int b = blockIdx.x >> 9, s = blockIdx.x & (SS - 1);
  const float4* base4 = xyz4 + (b << 13);
  float ax = kp[b * 1536 + s];
  float ay = kp[b * 1536 + SS + s];
  float az = kp[b * 1536 + 2 * SS + s];
  float aw = __fadd_rn(__fadd_rn(__fmul_rn(ax, ax), __fmul_rn(ay, ay)), __fmul_rn(az, az));
  u64 arr[KDB];
#pragma unroll
  for (int i = 0; i < KDB; ++i) arr[i] = ~0ull;
  for (int c = 0; c < 32; ++c) {
    int n = c * 256 + t;  // coalesced across the block, disjoint cover
    float4 q = base4[n];  // one dwordx4
    float dot = __fadd_rn(__fadd_rn(__fmul_rn(ax, q.x), __fmul_rn(ay, q.y)),
                          __fmul_rn(az, q.z));
    float d = __fsub_rn(__fadd_rn(aw, q.w), __fmul_rn(2.0f, dot));
    u32 ub = __float_as_uint(d);
    ub ^= (ub & 0x80000000u) ? 0xFFFFFFFFu : 0x80000000u;  // order-preserving map
    u64 key = ((u64)ub << 32) | (u32)n;
    if (key < arr[KDB - 1]) {  // sorted insert, CSE'd conditions
      bool cg[KDB];
#pragma unroll
      for (int i = 0; i < KDB; ++i) cg[i] = arr[i] > key;
#pragma unroll
      for (int i = KDB - 1; i >= 1; --i)
        arr[i] = cg[i - 1] ? arr[i - 1] : (cg[i] ? key : arr[i]);
      arr[0] = cg[0] ? key : arr[0];
    }
  }
  // phase A: per-wave merge of 64 sorted lists -> wave's sorted top-24
  u64 mine = 0;
  for (int it = 0; it < 24; ++it) {
    u64 mw = wave_min_u64(arr[0]);
    if (lane == it) mine = mw;
    if (arr[0] == mw) {  // unique keys -> exactly one popper
#pragma unroll
      for (int i = 0; i < KDB - 1; ++i) arr[i] = arr[i + 1];
      arr[KDB - 1] = ~0ull;
    }
  }
  if (lane < 24) skeys[w * 24 + lane] = mine;
  __syncthreads();
  // phase B: wave 0 merges the 4 sorted 24-lists (96 unique keys)
  if (w == 0) {
    u64 a = skeys[lane];
    u64 b2 = (lane < 32) ? skeys[64 + lane] : ~0ull;
    u64 lo = (a < b2) ? a : b2;
    u64 hi = (a < b2) ? b2 : a;
    u64 outk = 0;
    for (int it = 0; it < 24; ++it) {
      u64 mw = wave_min_u64(lo);
      if (lane == it) outk = mw;
      if (lo == mw) {
        lo = hi;
        hi = ~0ull;
      }
    }
    if (lane < 24) knn[blockIdx.x * 24 + lane] = (u16)(outk & 0xFFFFu);
  }
}

// ---------------------------------------------------------------------------
// Fallback solo KNN (workspace too small for float4): scalar path, 1 wave
// per row, KD=14.
// ---------------------------------------------------------------------------
__global__ __launch_bounds__(256) void k_knn_solo(const float* __restrict__ xyz,
                                                  const float* __restrict__ kp,
                                                  u16* __restrict__ knn) {
  int t = threadIdx.x;
  int row = blockIdx.x * 4 + (t >> 6);
  int lane = t & 63;
  int b = row >> 9, s = row & (SS - 1);
  const float* base = xyz + b * N3;
  float ax = kp[b * 1536 + s];
  float ay = kp[b * 1536 + SS + s];
  float az = kp[b * 1536 + 2 * SS + s];
  float aw = __fadd_rn(__fadd_rn(__fmul_rn(ax, ax), __fmul_rn(ay, ay)), __fmul_rn(az, az));
  u64 arr[KD];
#pragma unroll
  for (int i = 0; i < KD; ++i) arr[i] = ~0ull;
  for (int c = 0; c < 128; ++c) {
    int n = c * 64 + lane;
    float qx = base[n], qy = base[NN + n], qz = base[2 * NN + n];
    float qw = __fadd_rn(__fadd_rn(__fmul_rn(qx, qx), __fmul_rn(qy, qy)), __fmul_rn(qz, qz));
    float dot = __fadd_rn(__fadd_rn(__fmul_rn(ax, qx), __fmul_rn(ay, qy)), __fmul_rn(az, qz));
    float d = __fsub_rn(__fadd_rn(aw, qw), __fmul_rn(2.0f, dot));
    u32 ub = __float_as_uint(d);
    ub ^= (ub & 0x80000000u) ? 0xFFFFFFFFu : 0x80000000u;
    u64 key = ((u64)ub << 32) | (u32)n;
    if (key < arr[KD - 1]) {
      bool cg[KD];
#pragma unroll
      for (int i = 0; i < KD; ++i) cg[i] = arr[i] > key;
#pragma unroll
      for (int i = KD - 1; i >= 1; --i)
        arr[i] = cg[i - 1] ? arr[i - 1] : (cg[i] ? key : arr[i]);
      arr[0] = cg[0] ? key : arr[0];
    }
  }
  u64 mine = 0;
  for (int it = 0; it < 24; ++it) {
    u64 mw = wave_min_u64(arr[0]);
    if (lane == it) mine = mw;
    if (arr[0] == mw) {
#pragma unroll
      for (int i = 0; i < KD - 1; ++i) arr[i] = arr[i + 1];
      arr[KD - 1] = ~0ull;
    }
  }
  if (lane < 24) knn[row * 24 + lane] = (u16)(mine & 0xFFFFu);
}

// ---------------------------------------------------------------------------
// K3 (r22 verbatim — the proven best): fused base-SA + multi-scale MLPs,
// 256 thr, TWO channels/thread (wgtA/wgtB = 2-way ILP in h2). W2 staged
// TRANSPOSED into LDS once (coalesced global reads), wgt regs filled from LDS
// then ASM-PINNED (blocks remat). W2T buffer aliases sfeat/sh1 (dead after
// the fill). r23-r25 occupancy experiments all regressed — do not revisit.
// ---------------------------------------------------------------------------
template <int USE4>
__global__ __launch_bounds__(256) void k_mlp(
    const float* __restrict__ xyz, const float* __restrict__ pts,
    const float4* __restrict__ xyz4, const float4* __restrict__ pts4,
    const float* __restrict__ kp, const u16* __restrict__ knn,
    const float* __restrict__ W1, const float* __restrict__ b1,
    const float* __restrict__ W2, const float* __restrict__ b2,
    const float* __restrict__ msW1, const float* __restrict__ msb1,
    const float* __restrict__ msW2, const float* __restrict__ msb2,
    float* __restrict__ out) {
  __shared__ float smem[448 + 8320];  // persistent 448 | big 8320 (35KB)
  float* sW1T = smem;                 // [c][o] (384 base / 192 ms)
  float* sb1 = smem + 384;            // 64
  float* big = smem + 448;            // W2T during init; sfeat|sh1 in groups
  int t = threadIdx.x, lane = t & 63, w = t >> 6;
  int b = blockIdx.x >> 6, s0 = (blockIdx.x & 63) * 8;
  int scale = (int)blockIdx.y - 1;  // -1 for base plane
  float b2A, b2B;
  const float* W2src;
  if (blockIdx.y == 0) {
    for (int i = t; i < 384; i += 256) {
      int o = i / 6, c = i - o * 6;
      sW1T[c * 64 + o] = W1[i];
    }
    if (t < 64) sb1[t] = b1[t];
    W2src = W2;
    b2A = b2[lane];
    b2B = b2[lane + 64];
  } else {
    const float* W1s = msW1 + scale * 192;
    for (int i = t; i < 192; i += 256) {
      int o = i / 3, c = i - o * 3;
      sW1T[c * 64 + o] = W1s[i];
    }
    if (t < 64) sb1[t] = msb1[scale * 64 + t];
    W2src = msW2 + scale * 8192;
    b2A = msb2[scale * 128 + lane];
    b2B = msb2[scale * 128 + lane + 64];
  }
  // Stage W2 transposed: big[j*130 + row]. Global reads coalesced (32/thread);
  // LDS writes 2-way bank aliased (free).
  for (int i = t; i < 8192; i += 256) {
    int row = i >> 6, j = i & 63;
    big[j * 130 + row] = W2src[i];
  }
  __syncthreads();
  float wgtA[64], wgtB[64];
#pragma unroll
  for (int j = 0; j < 64; ++j) {
    wgtA[j] = big[j * 130 + lane];       // 2-way bank, free
    wgtB[j] = big[j * 130 + 64 + lane];  // ds_read2-pairable
  }
#pragma unroll
  for (int j = 0; j < 64; ++j) {
    // Opaque def: forces true VGPR residency (blocks remat/spill-reload).
    asm volatile("" : "+v"(wgtA[j]), "+v"(wgtB[j]));
  }
  __syncthreads();  // all reg fills done before groups overwrite `big`
  if (blockIdx.y == 0) {
    // ---------------- base plane ----------------
    float* sfeat = big;        // [row][k*6+c] 4*96
    float* sh1 = big + 384;    // [row][k*64+o] 4*1024
    for (int g = 0; g < 2; ++g) {
      if (t < 128) {  // 64 (rr,k) pairs x 2 halves: h=0 xyz, h=1 pts
        int p = t >> 1, h = t & 1;
        int rr = p >> 4, k = p & 15;
        int s = s0 + g * 4 + rr, row = b * SS + s;
        int id = knn[row * 24 + k];  // first 16 of sorted top-24 = base KNN
        float* f = &sfeat[rr * 96 + k * 6];
        if (h == 0) {
          float qx, qy, qz;
          if constexpr (USE4) {
            float4 q = xyz4[(b << 13) + id];
            qx = q.x; qy = q.y; qz = q.z;
          } else {
            qx = xyz[b * N3 + id];
            qy = xyz[b * N3 + NN + id];
            qz = xyz[b * N3 + 2 * NN + id];
          }
          f[0] = __fsub_rn(qx, kp[b * 1536 + s]);
          f[1] = __fsub_rn(qy, kp[b * 1536 + SS + s]);
          f[2] = __fsub_rn(qz, kp[b * 1536 + 2 * SS + s]);
        } else {
          float px_, py_, pz_;
          if constexpr (USE4) {
            float4 q = pts4[(b << 13) + id];
            px_ = q.x; py_ = q.y; pz_ = q.z;
          } else {
            px_ = pts[b * N3 + id];
            py_ = pts[b * N3 + NN + id];
            pz_ = pts[b * N3 + 2 * NN + id];
          }
          f[3] = px_;
          f[4] = py_;
          f[5] = pz_;
        }
      }
      __syncthreads();
#pragma unroll
      for (int m = 0; m < 16; ++m) {  // 4 rows x 1024 h1 entries / 256 thr
        int u = m * 256 + t;
        int rr = u >> 10, rem = u & 1023, k = rem >> 6, o = rem & 63;
        float acc = sb1[o];
#pragma unroll
        for (int c = 0; c < 6; ++c) acc = fmaf(sfeat[rr * 96 + k * 6 + c], sW1T[c * 64 + o], acc);
        sh1[rr * 1024 + k * 64 + o] = fmaxf(acc, 0.f);
      }
      __syncthreads();
      float bestA = -1e30f, bestB = -1e30f;
#pragma unroll
      for (int k = 0; k < 16; ++k) {
        const float4* h4 = (const float4*)&sh1[w * 1024 + k * 64];  // wave-uniform bcast
        float a0 = 0.f, a1 = 0.f;
#pragma unroll
        for (int j = 0; j < 16; ++j) {
          float4 hv = h4[j];
          a0 = fmaf(hv.x, wgtA[4 * j], a0);
          a0 = fmaf(hv.y, wgtA[4 * j + 1], a0);
          a0 = fmaf(hv.z, wgtA[4 * j + 2], a0);
          a0 = fmaf(hv.w, wgtA[4 * j + 3], a0);
          a1 = fmaf(hv.x, wgtB[4 * j], a1);
          a1 = fmaf(hv.y, wgtB[4 * j + 1], a1);
          a1 = fmaf(hv.z, wgtB[4 * j + 2], a1);
          a1 = fmaf(hv.w, wgtB[4 * j + 3], a1);
        }
        bestA = fmaxf(bestA, a0);
        bestB = fmaxf(bestB, a1);
      }
      int s = s0 + g * 4 + w;
      out[24576 + b * 262144 + lane * 512 + s] = bestA + b2A;
      out[24576 + b * 262144 + (lane + 64) * 512 + s] = bestB + b2B;
      __syncthreads();  // protect sfeat/sh1 before next group overwrites
    }
  } else {
    // ---------------- ms planes (kk = 8*(scale+1)) ----------------
    int kk = 8 * (scale + 1);
    float* sfeat = big;        // [row][k*3+c] 4*72
    float* sh1 = big + 288;    // [row][k*64+o] 4*1536
    int co = 128 * (scale + 1);
    for (int g = 0; g < 2; ++g) {
      if (t < 96) {  // 4 rows x 24 slots (stage all 24; h1 reads only k<kk)
        int rr = t / 24, k = t - rr * 24;  // constant divisor -> mul-shift
        int s = s0 + g * 4 + rr, row = b * SS + s;
        int id = knn[row * 24 + k];
        float qx, qy, qz;
        if constexpr (USE4) {
          float4 q = xyz4[(b << 13) + id];
          qx = q.x; qy = q.y; qz = q.z;
        } else {
          qx = xyz[b * N3 + id];
          qy = xyz[b * N3 + NN + id];
          qz = xyz[b * N3 + 2 * NN + id];
        }
        float* f = &sfeat[rr * 72 + k * 3];
        f[0] = __fsub_rn(qx, kp[b * 1536 + s]);
        f[1] = __fsub_rn(qy, kp[b * 1536 + SS + s]);
        f[2] = __fsub_rn(qz, kp[b * 1536 + 2 * SS + s]);
      }
      __syncthreads();
      for (int rr = 0; rr < 4; ++rr) {  // h1 for kk*64 entries per row
        for (int u = t; u < kk * 64; u += 256) {
          int k = u >> 6, o = u & 63;
          float acc = sb1[o];
          acc = fmaf(sfeat[rr * 72 + k * 3 + 0], sW1T[o], acc);
          acc = fmaf(sfeat[rr * 72 + k * 3 + 1], sW1T[64 + o], acc);
          acc = fmaf(sfeat[rr * 72 + k * 3 + 2], sW1T[128 + o], acc);
          sh1[rr * 1536 + k * 64 + o] = fmaxf(acc, 0.f);
        }
      }
      __syncthreads();
      float bestA = -1e30f, bestB = -1e30f;
      for (int k = 0; k < kk; ++k) {  // kk uniform across block -> no divergence
        const float4* h4 = (const float4*)&sh1[w * 1536 + k * 64];
        float a0 = 0.f, a1 = 0.f;
#pragma unroll
        for (int j = 0; j < 16; ++j) {
          float4 hv = h4[j];
          a0 = fmaf(hv.x, wgtA[4 * j], a0);
          a0 = fmaf(hv.y, wgtA[4 * j + 1], a0);
          a0 = fmaf(hv.z, wgtA[4 * j + 2], a0);
          a0 = fmaf(hv.w, wgtA[4 * j + 3], a0);
          a1 = fmaf(hv.x, wgtB[4 * j], a1);
          a1 = fmaf(hv.y, wgtB[4 * j + 1], a1);
          a1 = fmaf(hv.z, wgtB[4 * j + 2], a1);
          a1 = fmaf(hv.w, wgtB[4 * j + 3], a1);
        }
        bestA = fmaxf(bestA, a0);
        bestB = fmaxf(bestB, a1);
      }
      int s = s0 + g * 4 + w;
      out[24576 + b * 262144 + (co + lane) * 512 + s] = bestA + b2A;
      out[24576 + b * 262144 + (co + lane + 64) * 512 + s] = bestB + b2B;
      __syncthreads();
    }
  }
}

// ---------------------------------------------------------------------------
extern "C" void kernel_launch(void* const* d_in, const int* in_sizes, int n_in,
                              void* d_out, int out_size, void* d_ws, size_t ws_size,
                              hipStream_t stream) {
  const float* xyz = (const float*)d_in[0];    // l0_xyz  [B,3,N] f32
  const float* pts = (const float*)d_in[1];    // l0_points
  const float* sa_W1 = (const float*)d_in[2];  // [64,6]
  const float* sa_b1 = (const float*)d_in[3];  // [64]
  const float* sa_W2 = (const float*)d_in[4];  // [128,64]
  const float* sa_b2 = (const float*)d_in[5];  // [128]
  const float* ms_W1 = (const float*)d_in[6];  // [3,64,3]
  const float* ms_b1 = (const float*)d_in[7];  // [3,64]
  const float* ms_W2 = (const float*)d_in[8];  // [3,128,64]
  const float* ms_b2 = (const float*)d_in[9];  // [3,128]
  float* out = (float*)d_out;
  const float* kp = (const float*)d_out;  // keypoints written by k_fps

  // workspace: knn u16[B*S*24] = 393216 B, then xyz4/pts4 float4[B*N] = 2 MB each
  u16* knn = (u16*)d_ws;
  float4* xyz4 = (float4*)((char*)d_ws + 393216);
  float4* pts4 = xyz4 + BB * NN;
  const size_t need4 = 393216 + (size_t)2 * BB * NN * sizeof(float4);
  const bool use4 = ws_size >= need4;

  k_fps<<<BB + 128, 512, 0, stream>>>(xyz, pts, out, xyz4, pts4, use4 ? 1 : 0);
  if (use4) {
    k_knn_blk<<<BB * SS, 256, 0, stream>>>(xyz4, kp, knn);
    k_mlp<1><<<dim3(BB * 64, 4), 256, 0, stream>>>(xyz, pts, xyz4, pts4, kp, knn,
                                                   sa_W1, sa_b1, sa_W2, sa_b2,
                                                   ms_W1, ms_b1, ms_W2, ms_b2, out);
  } else {
    k_knn_solo<<<(BB * SS) / 4, 256, 0, stream>>>(xyz, kp, knn);
    k_mlp<0><<<dim3(BB * 64, 4), 256, 0, stream>>>(xyz, pts, xyz4, pts4, kp, knn,
                                                   sa_W1, sa_b1, sa_W2, sa_b2,
                                                   ms_W1, ms_b1, ms_W2, ms_b2, out);
  }
}

// Round 17
// 872.652 us; speedup vs baseline: 1.1823x; 1.0153x over previous
//
#include <hip/hip_runtime.h>

#define BB 16
#define NN 8192
#define SS 512
#define N3 (3 * NN)  // 24576 elements per batch per tensor
#define KD 14        // per-lane depth for the SOLO (1-wave-per-row) fallback
#define KDB 7        // per-lane depth for the block-per-row kernel (32 pts/lane)

typedef unsigned short u16;
typedef unsigned int u32;
typedef unsigned long long u64;
typedef float v2f __attribute__((ext_vector_type(2)));

// Packed fp32 ops (VOP3P, 2 points/inst). Per-half rounding is IEEE rn —
// bit-identical to scalar __fadd_rn/__fmul_rn.
__device__ __forceinline__ v2f pk_add(v2f a, v2f b) {
  v2f r;
  asm("v_pk_add_f32 %0, %1, %2" : "=v"(r) : "v"(a), "v"(b));
  return r;
}
__device__ __forceinline__ v2f pk_mul(v2f a, v2f b) {
  v2f r;
  asm("v_pk_mul_f32 %0, %1, %2" : "=v"(r) : "v"(a), "v"(b));
  return r;
}

// u64 max step over a DPP lane-shift (FPS): old=0 is the max identity for our
// positive keys.
template <int CTRL>
__device__ __forceinline__ u64 dpp_maxk(u64 k) {
  u32 lo = (u32)k, hi = (u32)(k >> 32);
  u32 slo = (u32)__builtin_amdgcn_update_dpp(0, (int)lo, CTRL, 0xf, 0xf, false);
  u32 shi = (u32)__builtin_amdgcn_update_dpp(0, (int)hi, CTRL, 0xf, 0xf, false);
  u64 s = ((u64)shi << 32) | (u64)slo;
  return (s > k) ? s : k;
}
// u64 MIN step over a DPP lane-shift (KNN merges): old=self is the min
// identity.
template <int CTRL>
__device__ __forceinline__ u64 dpp_mink(u64 k) {
  u32 lo = (u32)k, hi = (u32)(k >> 32);
  u32 slo = (u32)__builtin_amdgcn_update_dpp((int)lo, (int)lo, CTRL, 0xf, 0xf, false);
  u32 shi = (u32)__builtin_amdgcn_update_dpp((int)hi, (int)hi, CTRL, 0xf, 0xf, false);
  u64 s = ((u64)shi << 32) | (u64)slo;
  return (s < k) ? s : k;
}
__device__ __forceinline__ u64 maxk(u64 a, u64 b) { return (a > b) ? a : b; }

// wave-min of `m` to ALL-lanes-usable form: 6-step DPP chain -> lane63, then
// 2 readlanes -> SGPR-uniform u64.
__device__ __forceinline__ u64 wave_min_u64(u64 m) {
  m = dpp_mink<0x111>(m);  // row_shr:1
  m = dpp_mink<0x112>(m);  // row_shr:2
  m = dpp_mink<0x114>(m);  // row_shr:4
  m = dpp_mink<0x118>(m);  // row_shr:8
  m = dpp_mink<0x142>(m);  // row_bcast:15
  m = dpp_mink<0x143>(m);  // row_bcast:31 -> lane63 = wave min
  u32 mlo = (u32)__builtin_amdgcn_readlane((int)(u32)m, 63);
  u32 mhi = (u32)__builtin_amdgcn_readlane((int)(u32)(m >> 32), 63);
  return ((u64)mhi << 32) | (u64)mlo;
}

// ---------------------------------------------------------------------------
// K1 (r26 config, proven best): FPS at 512 thr = 2 waves/SIMD (measured
// optimum: 1w 544, 2w 508-512, 4w-lean 669) + prep (blocks 16..143, LDS-free,
// zero inter-block communication; stream order fences k_knn; prep fully
// hidden under FPS). Bit-exact vs numpy (see prior notes).
// ---------------------------------------------------------------------------
__global__ __attribute__((amdgpu_flat_work_group_size(512, 512),
                          amdgpu_waves_per_eu(2, 2)))
void k_fps(const float* __restrict__ xyz, const float* __restrict__ pts,
           float* __restrict__ out_kp, float4* __restrict__ xyz4,
           float4* __restrict__ pts4, int do_prep) {
  __shared__ float sxyz[NN * 3];  // [idx][x,y,z] (FPS blocks only)
  __shared__ int sIdx[SS];
  __shared__ u64 rkey[2][8];
  int t = threadIdx.x;
  if (blockIdx.x >= BB) {
    // ---------------- prep plane ----------------
    if (do_prep) {
      int e0 = (blockIdx.x - BB) * 1024 + t;  // 128 blocks x 1024 elems
#pragma unroll
      for (int r = 0; r < 2; ++r) {
        int e = e0 + r * 512;  // coalesced; covers [0, BB*NN)
        int b = e >> 13, n = e & (NN - 1);
        const float* xb = xyz + b * N3;
        float x = xb[n], y = xb[NN + n], z = xb[2 * NN + n];
        float ww = __fadd_rn(__fadd_rn(__fmul_rn(x, x), __fmul_rn(y, y)),
                             __fmul_rn(z, z));
        xyz4[e] = make_float4(x, y, z, ww);
        const float* pb = pts + b * N3;
        pts4[e] = make_float4(pb[n], pb[NN + n], pb[2 * NN + n], 0.f);
      }
    }
    return;
  }
  // ---------------- FPS ----------------
  int b = blockIdx.x;
  const float* base = xyz + b * N3;
  v2f px[8], py[8], pz[8], dm[8];
#pragma unroll
  for (int j = 0; j < 8; ++j) {
    int n0 = j * 1024 + t, n1 = n0 + 512;  // coalesced, disjoint cover [0,8192)
    px[j] = v2f{base[n0], base[n1]};
    py[j] = v2f{base[NN + n0], base[NN + n1]};
    pz[j] = v2f{base[2 * NN + n0], base[2 * NN + n1]};
    dm[j] = v2f{1e10f, 1e10f};
    sxyz[n0 * 3 + 0] = px[j].x;  // stage AoS copy for center re-loads
    sxyz[n0 * 3 + 1] = py[j].x;
    sxyz[n0 * 3 + 2] = pz[j].x;
    sxyz[n1 * 3 + 0] = px[j].y;
    sxyz[n1 * 3 + 1] = py[j].y;
    sxyz[n1 * 3 + 2] = pz[j].y;
  }
#pragma unroll
  for (int j = 0; j < 8; ++j) {
    // Opaque def: blocks rematerialization of the global loads.
    asm volatile("" : "+v"(px[j]), "+v"(py[j]), "+v"(pz[j]));
  }
  float cx = base[0], cy = base[NN], cz = base[2 * NN];
  int far = 0;
  int lane = t & 63, w = t >> 6;
  u32 tb = (u32)(NN - t);  // candidate base: cand = NN - gidx (1..8192; 0=none)
  for (int it = 0; it < SS; ++it) {
    if (t == 0) sIdx[it] = far;  // scan emits carry BEFORE update: idx[0]=0
    v2f ncx = v2f{-cx, -cx}, ncy = v2f{-cy, -cy}, ncz = v2f{-cz, -cz};
    float vmax = 0.0f;
#pragma unroll
    for (int j = 0; j < 8; ++j) {
      v2f dx = pk_add(px[j], ncx);
      v2f dy = pk_add(py[j], ncy);
      v2f dz = pk_add(pz[j], ncz);
      v2f xx = pk_mul(dx, dx);
      v2f yy = pk_mul(dy, dy);
      v2f s = pk_add(xx, yy);
      v2f zz = pk_mul(dz, dz);
      v2f d = pk_add(s, zz);  // ((dx^2+dy^2)+dz^2), numpy tree per half
      float a0 = fminf(dm[j].x, d.x);
      float a1 = fminf(dm[j].y, d.y);
      dm[j].x = a0;
      dm[j].y = a1;
      vmax = fmaxf(vmax, fmaxf(a0, a1));  // max3-foldable
    }
    u32 cand = 0;
#pragma unroll
    for (int j = 7; j >= 0; --j) {
      u32 v1 = tb - (u32)(j * 1024 + 512);  // cand for .y half (higher gidx)
      u32 v0 = tb - (u32)(j * 1024);        // cand for .x half
      cand = (dm[j].y == vmax) ? v1 : cand;
      cand = (dm[j].x == vmax) ? v0 : cand;
    }
    u64 key = ((u64)__float_as_uint(vmax) << 32) | cand;
    key = dpp_maxk<0x111>(key);  // row_shr:1
    key = dpp_maxk<0x112>(key);  // row_shr:2
    key = dpp_maxk<0x114>(key);  // row_shr:4
    key = dpp_maxk<0x118>(key);  // row_shr:8
    key = dpp_maxk<0x142>(key);  // row_bcast:15
    key = dpp_maxk<0x143>(key);  // row_bcast:31 -> lane63 = wave max
    int pb = it & 1;  // parity double-buffer: safe with one barrier/iter
    if (lane == 63) rkey[pb][w] = key;
    __syncthreads();  // the only barrier per iteration
    u64 k0 = rkey[pb][0], k1 = rkey[pb][1];
    u64 k2 = rkey[pb][2], k3 = rkey[pb][3];
    u64 k4 = rkey[pb][4], k5 = rkey[pb][5];
    u64 k6 = rkey[pb][6], k7 = rkey[pb][7];
    u64 kg = maxk(maxk(maxk(k0, k1), maxk(k2, k3)),
                  maxk(maxk(k4, k5), maxk(k6, k7)));
    far = NN - (int)(u32)(kg & 0xffffffffu);
    cx = sxyz[far * 3 + 0];
    cy = sxyz[far * 3 + 1];
    cz = sxyz[far * 3 + 2];
  }
  __syncthreads();
  for (int i = t; i < SS; i += 512) {
    int id = sIdx[i];
    out_kp[b * 1536 + i] = base[id];  // exact fp32 copies
    out_kp[b * 1536 + SS + i] = base[NN + id];
    out_kp[b * 1536 + 2 * SS + i] = base[2 * NN + id];
  }
}

// ---------------------------------------------------------------------------
// K2 (r21, unchanged): one ROW per 256-thread BLOCK. 32 pts/lane, KDB=7
// (failure odds ~8e-8/run). 3-level exact min-extract merge -> bit-identical
// to the 1-wave version. 985 -> 904 us win.
// ---------------------------------------------------------------------------
__global__ __launch_bounds__(256) void k_knn_blk(const float4* __restrict__ xyz4,
                                                 const float* __restrict__ kp,
                                                 u16* __restrict__ knn) {
  __shared__ u64 skeys[96];
  int t = threadIdx.x, lane = t & 63, w = t >> 6;
  int b = blockIdx.x >> 9, s = blockIdx.x & (SS - 1);
  const float4* base4 = xyz4 + (b << 13);
  float ax = kp[b * 1536 + s];
  float ay = kp[b * 1536 + SS + s];
  float az = kp[b * 1536 + 2 * SS + s];
  float aw = __fadd_rn(__fadd_rn(__fmul_rn(ax, ax), __fmul_rn(ay, ay)), __fmul_rn(az, az));
  u64 arr[KDB];
#pragma unroll
  for (int i = 0; i < KDB; ++i) arr[i] = ~0ull;
  for (int c = 0; c < 32; ++c) {
    int n = c * 256 + t;  // coalesced across the block, disjoint cover
    float4 q = base4[n];  // one dwordx4
    float dot = __fadd_rn(__fadd_rn(__fmul_rn(ax, q.x), __fmul_rn(ay, q.y)),
                          __fmul_rn(az, q.z));
    float d = __fsub_rn(__fadd_rn(aw, q.w), __fmul_rn(2.0f, dot));
    u32 ub = __float_as_uint(d);
    ub ^= (ub & 0x80000000u) ? 0xFFFFFFFFu : 0x80000000u;  // order-preserving map
    u64 key = ((u64)ub << 32) | (u32)n;
    if (key < arr[KDB - 1]) {  // sorted insert, CSE'd conditions
      bool cg[KDB];
#pragma unroll
      for (int i = 0; i < KDB; ++i) cg[i] = arr[i] > key;
#pragma unroll
      for (int i = KDB - 1; i >= 1; --i)
        arr[i] = cg[i - 1] ? arr[i - 1] : (cg[i] ? key : arr[i]);
      arr[0] = cg[0] ? key : arr[0];
    }
  }
  // phase A: per-wave merge of 64 sorted lists -> wave's sorted top-24
  u64 mine = 0;
  for (int it = 0; it < 24; ++it) {
    u64 mw = wave_min_u64(arr[0]);
    if (lane == it) mine = mw;
    if (arr[0] == mw) {  // unique keys -> exactly one popper
#pragma unroll
      for (int i = 0; i < KDB - 1; ++i) arr[i] = arr[i + 1];
      arr[KDB - 1] = ~0ull;
    }
  }
  if (lane < 24) skeys[w * 24 + lane] = mine;
  __syncthreads();
  // phase B: wave 0 merges the 4 sorted 24-lists (96 unique keys)
  if (w == 0) {
    u64 a = skeys[lane];
    u64 b2 = (lane < 32) ? skeys[64 + lane] : ~0ull;
    u64 lo = (a < b2) ? a : b2;
    u64 hi = (a < b2) ? b2 : a;
    u64 outk = 0;
    for (int it = 0; it < 24; ++it) {
      u64 mw = wave_min_u64(lo);
      if (lane == it) outk = mw;
      if (lo == mw) {
        lo = hi;
        hi = ~0ull;
      }
    }
    if (lane < 24) knn[blockIdx.x * 24 + lane] = (u16)(outk & 0xFFFFu);
  }
}

// ---------------------------------------------------------------------------
// Fallback solo KNN (workspace too small for float4): scalar path, 1 wave
// per row, KD=14.
// ---------------------------------------------------------------------------
__global__ __launch_bounds__(256) void k_knn_solo(const float* __restrict__ xyz,
                                                  const float* __restrict__ kp,
                                                  u16* __restrict__ knn) {
  int t = threadIdx.x;
  int row = blockIdx.x * 4 + (t >> 6);
  int lane = t & 63;
  int b = row >> 9, s = row & (SS - 1);
  const float* base = xyz + b * N3;
  float ax = kp[b * 1536 + s];
  float ay = kp[b * 1536 + SS + s];
  float az = kp[b * 1536 + 2 * SS + s];
  float aw = __fadd_rn(__fadd_rn(__fmul_rn(ax, ax), __fmul_rn(ay, ay)), __fmul_rn(az, az));
  u64 arr[KD];
#pragma unroll
  for (int i = 0; i < KD; ++i) arr[i] = ~0ull;
  for (int c = 0; c < 128; ++c) {
    int n = c * 64 + lane;
    float qx = base[n], qy = base[NN + n], qz = base[2 * NN + n];
    float qw = __fadd_rn(__fadd_rn(__fmul_rn(qx, qx), __fmul_rn(qy, qy)), __fmul_rn(qz, qz));
    float dot = __fadd_rn(__fadd_rn(__fmul_rn(ax, qx), __fmul_rn(ay, qy)), __fmul_rn(az, qz));
    float d = __fsub_rn(__fadd_rn(aw, qw), __fmul_rn(2.0f, dot));
    u32 ub = __float_as_uint(d);
    ub ^= (ub & 0x80000000u) ? 0xFFFFFFFFu : 0x80000000u;
    u64 key = ((u64)ub << 32) | (u32)n;
    if (key < arr[KD - 1]) {
      bool cg[KD];
#pragma unroll
      for (int i = 0; i < KD; ++i) cg[i] = arr[i] > key;
#pragma unroll
      for (int i = KD - 1; i >= 1; --i)
        arr[i] = cg[i - 1] ? arr[i - 1] : (cg[i] ? key : arr[i]);
      arr[0] = cg[0] ? key : arr[0];
    }
  }
  u64 mine = 0;
  for (int it = 0; it < 24; ++it) {
    u64 mw = wave_min_u64(arr[0]);
    if (lane == it) mine = mw;
    if (arr[0] == mw) {
#pragma unroll
      for (int i = 0; i < KD - 1; ++i) arr[i] = arr[i + 1];
      arr[KD - 1] = ~0ull;
    }
  }
  if (lane < 24) knn[row * 24 + lane] = (u16)(mine & 0xFFFFu);
}

// ---------------------------------------------------------------------------
// ms-plane group body with COMPILE-TIME KK (r29): the base plane's h2 loop is
// fully unrolled (k=16 const) so the compiler pipelines its 256 LDS broadcast
// loads; the ms planes (3/4 of k_mlp's work) previously used runtime kk ->
// no unroll -> ~90cy head-of-iteration lgkm stall paid EVERY k. Dispatching
// through template<KK> gives every loop a constant trip count. Same fma/fmax
// order, same barriers -> bit-identical.
// ---------------------------------------------------------------------------
template <int USE4, int KK>
__device__ __forceinline__ void ms_group(
    int t, int lane, int w, int b, int s0, int g, int co,
    const float* __restrict__ xyz, const float4* __restrict__ xyz4,
    const float* __restrict__ kp, const u16* __restrict__ knn,
    float* sfeat, float* sh1, const float* sW1T, const float* sb1,
    const float (&wgtA)[64], const float (&wgtB)[64], float b2A, float b2B,
    float* __restrict__ out) {
  if (t < 96) {  // 4 rows x 24 slots (stage all 24; h1 reads only k<KK)
    int rr = t / 24, k = t - rr * 24;  // constant divisor -> mul-shift
    int s = s0 + g * 4 + rr, row = b * SS + s;
    int id = knn[row * 24 + k];
    float qx, qy, qz;
    if constexpr (USE4) {
      float4 q = xyz4[(b << 13) + id];
      qx = q.x; qy = q.y; qz = q.z;
    } else {
      qx = xyz[b * N3 + id];
      qy = xyz[b * N3 + NN + id];
      qz = xyz[b * N3 + 2 * NN + id];
    }
    float* f = &sfeat[rr * 72 + k * 3];
    f[0] = __fsub_rn(qx, kp[b * 1536 + s]);
    f[1] = __fsub_rn(qy, kp[b * 1536 + SS + s]);
    f[2] = __fsub_rn(qz, kp[b * 1536 + 2 * SS + s]);
  }
  __syncthreads();
  for (int rr = 0; rr < 4; ++rr) {  // h1: KK*64 entries per row, const trips
#pragma unroll
    for (int u0 = 0; u0 < KK * 64; u0 += 256) {
      int u = u0 + t;
      int k = u >> 6, o = u & 63;
      float acc = sb1[o];
      acc = fmaf(sfeat[rr * 72 + k * 3 + 0], sW1T[o], acc);
      acc = fmaf(sfeat[rr * 72 + k * 3 + 1], sW1T[64 + o], acc);
      acc = fmaf(sfeat[rr * 72 + k * 3 + 2], sW1T[128 + o], acc);
      sh1[rr * 1536 + k * 64 + o] = fmaxf(acc, 0.f);
    }
  }
  __syncthreads();
  float bestA = -1e30f, bestB = -1e30f;
#pragma unroll
  for (int k = 0; k < KK; ++k) {  // const trip -> loads pipelined across k
    const float4* h4 = (const float4*)&sh1[w * 1536 + k * 64];
    float a0 = 0.f, a1 = 0.f;
#pragma unroll
    for (int j = 0; j < 16; ++j) {
      float4 hv = h4[j];
      a0 = fmaf(hv.x, wgtA[4 * j], a0);
      a0 = fmaf(hv.y, wgtA[4 * j + 1], a0);
      a0 = fmaf(hv.z, wgtA[4 * j + 2], a0);
      a0 = fmaf(hv.w, wgtA[4 * j + 3], a0);
      a1 = fmaf(hv.x, wgtB[4 * j], a1);
      a1 = fmaf(hv.y, wgtB[4 * j + 1], a1);
      a1 = fmaf(hv.z, wgtB[4 * j + 2], a1);
      a1 = fmaf(hv.w, wgtB[4 * j + 3], a1);
    }
    bestA = fmaxf(bestA, a0);
    bestB = fmaxf(bestB, a1);
  }
  int s = s0 + g * 4 + w;
  out[24576 + b * 262144 + (co + lane) * 512 + s] = bestA + b2A;
  out[24576 + b * 262144 + (co + lane + 64) * 512 + s] = bestB + b2B;
  __syncthreads();
}

// ---------------------------------------------------------------------------
// K3 (r29 = r22 body + const-KK ms dispatch): fused base-SA + multi-scale
// MLPs, 256 thr, TWO channels/thread (2-way ILP in h2). W2 staged TRANSPOSED
// into LDS once, wgt regs ASM-PINNED (blocks remat). W2T buffer aliases
// sfeat/sh1. r23-r25 occupancy experiments all regressed — do not revisit.
// ---------------------------------------------------------------------------
template <int USE4>
__global__ __launch_bounds__(256) void k_mlp(
    const float* __restrict__ xyz, const float* __restrict__ pts,
    const float4* __restrict__ xyz4, const float4* __restrict__ pts4,
    const float* __restrict__ kp, const u16* __restrict__ knn,
    const float* __restrict__ W1, const float* __restrict__ b1,
    const float* __restrict__ W2, const float* __restrict__ b2,
    const float* __restrict__ msW1, const float* __restrict__ msb1,
    const float* __restrict__ msW2, const float* __restrict__ msb2,
    float* __restrict__ out) {
  __shared__ float smem[448 + 8320];  // persistent 448 | big 8320 (35KB)
  float* sW1T = smem;                 // [c][o] (384 base / 192 ms)
  float* sb1 = smem + 384;            // 64
  float* big = smem + 448;            // W2T during init; sfeat|sh1 in groups
  int t = threadIdx.x, lane = t & 63, w = t >> 6;
  int b = blockIdx.x >> 6, s0 = (blockIdx.x & 63) * 8;
  int scale = (int)blockIdx.y - 1;  // -1 for base plane
  float b2A, b2B;
  const float* W2src;
  if (blockIdx.y == 0) {
    for (int i = t; i < 384; i += 256) {
      int o = i / 6, c = i - o * 6;
      sW1T[c * 64 + o] = W1[i];
    }
    if (t < 64) sb1[t] = b1[t];
    W2src = W2;
    b2A = b2[lane];
    b2B = b2[lane + 64];
  } else {
    const float* W1s = msW1 + scale * 192;
    for (int i = t; i < 192; i += 256) {
      int o = i / 3, c = i - o * 3;
      sW1T[c * 64 + o] = W1s[i];
    }
    if (t < 64) sb1[t] = msb1[scale * 64 + t];
    W2src = msW2 + scale * 8192;
    b2A = msb2[scale * 128 + lane];
    b2B = msb2[scale * 128 + lane + 64];
  }
  // Stage W2 transposed: big[j*130 + row]. Global reads coalesced (32/thread);
  // LDS writes 2-way bank aliased (free).
  for (int i = t; i < 8192; i += 256) {
    int row = i >> 6, j = i & 63;
    big[j * 130 + row] = W2src[i];
  }
  __syncthreads();
  float wgtA[64], wgtB[64];
#pragma unroll
  for (int j = 0; j < 64; ++j) {
    wgtA[j] = big[j * 130 + lane];       // 2-way bank, free
    wgtB[j] = big[j * 130 + 64 + lane];  // ds_read2-pairable
  }
#pragma unroll
  for (int j = 0; j < 64; ++j) {
    // Opaque def: forces true VGPR residency (blocks remat/spill-reload).
    asm volatile("" : "+v"(wgtA[j]), "+v"(wgtB[j]));
  }
  __syncthreads();  // all reg fills done before groups overwrite `big`
  if (blockIdx.y == 0) {
    // ---------------- base plane ----------------
    float* sfeat = big;        // [row][k*6+c] 4*96
    float* sh1 = big + 384;    // [row][k*64+o] 4*1024
    for (int g = 0; g < 2; ++g) {
      if (t < 128) {  // 64 (rr,k) pairs x 2 halves: h=0 xyz, h=1 pts
        int p = t >> 1, h = t & 1;
        int rr = p >> 4, k = p & 15;
        int s = s0 + g * 4 + rr, row = b * SS + s;
        int id = knn[row * 24 + k];  // first 16 of sorted top-24 = base KNN
        float* f = &sfeat[rr * 96 + k * 6];
        if (h == 0) {
          float qx, qy, qz;
          if constexpr (USE4) {
            float4 q = xyz4[(b << 13) + id];
            qx = q.x; qy = q.y; qz = q.z;
          } else {
            qx = xyz[b * N3 + id];
            qy = xyz[b * N3 + NN + id];
            qz = xyz[b * N3 + 2 * NN + id];
          }
          f[0] = __fsub_rn(qx, kp[b * 1536 + s]);
          f[1] = __fsub_rn(qy, kp[b * 1536 + SS + s]);
          f[2] = __fsub_rn(qz, kp[b * 1536 + 2 * SS + s]);
        } else {
          float px_, py_, pz_;
          if constexpr (USE4) {
            float4 q = pts4[(b << 13) + id];
            px_ = q.x; py_ = q.y; pz_ = q.z;
          } else {
            px_ = pts[b * N3 + id];
            py_ = pts[b * N3 + NN + id];
            pz_ = pts[b * N3 + 2 * NN + id];
          }
          f[3] = px_;
          f[4] = py_;
          f[5] = pz_;
        }
      }
      __syncthreads();
#pragma unroll
      for (int m = 0; m < 16; ++m) {  // 4 rows x 1024 h1 entries / 256 thr
        int u = m * 256 + t;
        int rr = u >> 10, rem = u & 1023, k = rem >> 6, o = rem & 63;
        float acc = sb1[o];
#pragma unroll
        for (int c = 0; c < 6; ++c) acc = fmaf(sfeat[rr * 96 + k * 6 + c], sW1T[c * 64 + o], acc);
        sh1[rr * 1024 + k * 64 + o] = fmaxf(acc, 0.f);
      }
      __syncthreads();
      float bestA = -1e30f, bestB = -1e30f;
#pragma unroll
      for (int k = 0; k < 16; ++k) {
        const float4* h4 = (const float4*)&sh1[w * 1024 + k * 64];  // wave-uniform bcast
        float a0 = 0.f, a1 = 0.f;
#pragma unroll
        for (int j = 0; j < 16; ++j) {
          float4 hv = h4[j];
          a0 = fmaf(hv.x, wgtA[4 * j], a0);
          a0 = fmaf(hv.y, wgtA[4 * j + 1], a0);
          a0 = fmaf(hv.z, wgtA[4 * j + 2], a0);
          a0 = fmaf(hv.w, wgtA[4 * j + 3], a0);
          a1 = fmaf(hv.x, wgtB[4 * j], a1);
          a1 = fmaf(hv.y, wgtB[4 * j + 1], a1);
          a1 = fmaf(hv.z, wgtB[4 * j + 2], a1);
          a1 = fmaf(hv.w, wgtB[4 * j + 3], a1);
        }
        bestA = fmaxf(bestA, a0);
        bestB = fmaxf(bestB, a1);
      }
      int s = s0 + g * 4 + w;
      out[24576 + b * 262144 + lane * 512 + s] = bestA + b2A;
      out[24576 + b * 262144 + (lane + 64) * 512 + s] = bestB + b2B;
      __syncthreads();  // protect sfeat/sh1 before next group overwrites
    }
  } else {
    // ---------------- ms planes (kk = 8*(scale+1)) ----------------
    int kk = 8 * (scale + 1);
    float* sfeat = big;        // [row][k*3+c] 4*72
    float* sh1 = big + 288;    // [row][k*64+o] 4*1536
    int co = 128 * (scale + 1);
    if (kk == 8) {
      for (int g = 0; g < 2; ++g)
        ms_group<USE4, 8>(t, lane, w, b, s0, g, co, xyz, xyz4, kp, knn,
                          sfeat, sh1, sW1T, sb1, wgtA, wgtB, b2A, b2B, out);
    } else if (kk == 16) {
      for (int g = 0; g < 2; ++g)
        ms_group<USE4, 16>(t, lane, w, b, s0, g, co, xyz, xyz4, kp, knn,
                           sfeat, sh1, sW1T, sb1, wgtA, wgtB, b2A, b2B, out);
    } else {
      for (int g = 0; g < 2; ++g)
        ms_group<USE4, 24>(t, lane, w, b, s0, g, co, xyz, xyz4, kp, knn,
                           sfeat, sh1, sW1T, sb1, wgtA, wgtB, b2A, b2B, out);
    }
  }
}

// ---------------------------------------------------------------------------
extern "C" void kernel_launch(void* const* d_in, const int* in_sizes, int n_in,
                              void* d_out, int out_size, void* d_ws, size_t ws_size,
                              hipStream_t stream) {
  const float* xyz = (const float*)d_in[0];    // l0_xyz  [B,3,N] f32
  const float* pts = (const float*)d_in[1];    // l0_points
  const float* sa_W1 = (const float*)d_in[2];  // [64,6]
  const float* sa_b1 = (const float*)d_in[3];  // [64]
  const float* sa_W2 = (const float*)d_in[4];  // [128,64]
  const float* sa_b2 = (const float*)d_in[5];  // [128]
  const float* ms_W1 = (const float*)d_in[6];  // [3,64,3]
  const float* ms_b1 = (const float*)d_in[7];  // [3,64]
  const float* ms_W2 = (const float*)d_in[8];  // [3,128,64]
  const float* ms_b2 = (const float*)d_in[9];  // [3,128]
  float* out = (float*)d_out;
  const float* kp = (const float*)d_out;  // keypoints written by k_fps

  // workspace: knn u16[B*S*24] = 393216 B, then xyz4/pts4 float4[B*N] = 2 MB each
  u16* knn = (u16*)d_ws;
  float4* xyz4 = (float4*)((char*)d_ws + 393216);
  float4* pts4 = xyz4 + BB * NN;
  const size_t need4 = 393216 + (size_t)2 * BB * NN * sizeof(float4);
  const bool use4 = ws_size >= need4;

  k_fps<<<BB + 128, 512, 0, stream>>>(xyz, pts, out, xyz4, pts4, use4 ? 1 : 0);
  if (use4) {
    k_knn_blk<<<BB * SS, 256, 0, stream>>>(xyz4, kp, knn);
    k_mlp<1><<<dim3(BB * 64, 4), 256, 0, stream>>>(xyz, pts, xyz4, pts4, kp, knn,
                                                   sa_W1, sa_b1, sa_W2, sa_b2,
                                                   ms_W1, ms_b1, ms_W2, ms_b2, out);
  } else {
    k_knn_solo<<<(BB * SS) / 4, 256, 0, stream>>>(xyz, kp, knn);
    k_mlp<0><<<dim3(BB * 64, 4), 256, 0, stream>>>(xyz, pts, xyz4, pts4, kp, knn,
                                                   sa_W1, sa_b1, sa_W2, sa_b2,
                                                   ms_W1, ms_b1, ms_W2, ms_b2, out);
  }
}